// Round 1
// baseline (333.048 us; speedup 1.0000x reference)
//
#include <hip/hip_runtime.h>
#include <math.h>

#define NAGENT 4096
#define TOPK 32

// ---------------------------------------------------------------------------
// Kernel 1: exact top-32 nearest neighbors per agent.
// Key = (float_bits(d) << 32) | j  -> min key == smallest d, ties lower index,
// exactly matching jax.lax.top_k(-d, 32) semantics.
// d = sqrt((dx*dx + dy*dy) + 1e-4) with rounding-faithful (non-contracted) ops.
// ---------------------------------------------------------------------------
__global__ __launch_bounds__(256) void topk_kernel(
    const float* __restrict__ states, int* __restrict__ idx_out)
{
    const int i = blockIdx.x;
    const int t = threadIdx.x;
    __shared__ unsigned int dbits[NAGENT];          // 16 KB
    __shared__ unsigned long long red[4];

    const float xi = states[i * 4 + 0];
    const float yi = states[i * 4 + 1];

    #pragma unroll
    for (int u = 0; u < NAGENT / 256; ++u) {
        int j = t + u * 256;
        float dx = __fsub_rn(xi, states[j * 4 + 0]);
        float dy = __fsub_rn(yi, states[j * 4 + 1]);
        float s  = __fadd_rn(__fadd_rn(__fmul_rn(dx, dx), __fmul_rn(dy, dy)), 1e-4f);
        float d  = sqrtf(s);
        dbits[j] = __float_as_uint(d);
    }
    __syncthreads();

    for (int k = 0; k < TOPK; ++k) {
        unsigned long long best = ~0ull;
        #pragma unroll
        for (int u = 0; u < NAGENT / 256; ++u) {
            int j = t + u * 256;
            unsigned long long key =
                ((unsigned long long)dbits[j] << 32) | (unsigned long long)(unsigned)j;
            if (key < best) best = key;
        }
        // wave (64-lane) butterfly min
        #pragma unroll
        for (int off = 1; off < 64; off <<= 1) {
            unsigned long long o = __shfl_xor(best, off, 64);
            if (o < best) best = o;
        }
        if ((t & 63) == 0) red[t >> 6] = best;
        __syncthreads();
        if (t == 0) {
            unsigned long long m = red[0];
            if (red[1] < m) m = red[1];
            if (red[2] < m) m = red[2];
            if (red[3] < m) m = red[3];
            int j = (int)(m & 0xffffffffull);
            idx_out[i * TOPK + k] = j;
            dbits[j] = 0xffffffffu;   // remove from candidate set
        }
        __syncthreads();
    }
}

// ---------------------------------------------------------------------------
// Kernel 2: fused per-agent network. One block (256 thr) per agent.
// Reproduces the reference exactly, including the raw reshape [K,5]->[5,K]
// (h[c][p] = flat[c*32+p], flat[k*5+f] = xk[k][f]) and argmax-as-feature.
// ---------------------------------------------------------------------------
__global__ __launch_bounds__(256) void mlp_kernel(
    const float* __restrict__ states, const float* __restrict__ goals,
    const float* __restrict__ W1,  const float* __restrict__ b1,
    const float* __restrict__ W2,  const float* __restrict__ b2,
    const float* __restrict__ Wd1, const float* __restrict__ bd1,
    const float* __restrict__ Wd2, const float* __restrict__ bd2,
    const float* __restrict__ Wd3, const float* __restrict__ bd3,
    const float* __restrict__ Wd4, const float* __restrict__ bd4,
    const int* __restrict__ idx_in, float* __restrict__ out)
{
    const int i = blockIdx.x;
    const int t = threadIdx.x;

    __shared__ float flat[TOPK * 5];   // 160: flat[k*5+f] = xk[k][f]
    __shared__ float maskv[TOPK];
    __shared__ float h1[64 * 32];      // 8 KB
    __shared__ float w2t[64 * 128];    // 32 KB, W2 transposed: w2t[c][o]
    __shared__ float h2m[128 * 32];    // 16 KB, relu(h2)+mask applied
    __shared__ float feat[132];
    __shared__ float z1s[64];
    __shared__ float z2s[128];
    __shared__ float z3s[64];
    __shared__ float z4s[4];

    // stage W2 transposed into LDS (coalesced global read, scattered LDS write)
    #pragma unroll
    for (int u = 0; u < 32; ++u) {
        int e = t + u * 256;
        int o = e >> 6, c = e & 63;
        w2t[c * 128 + o] = W2[e];
    }

    if (t < TOPK) {
        int j = idx_in[i * TOPK + t];
        float d0 = states[i * 4 + 0] - states[j * 4 + 0];
        float d1 = states[i * 4 + 1] - states[j * 4 + 1];
        float d2 = states[i * 4 + 2] - states[j * 4 + 2];
        float d3 = states[i * 4 + 3] - states[j * 4 + 3];
        flat[t * 5 + 0] = d0;
        flat[t * 5 + 1] = d1;
        flat[t * 5 + 2] = d2;
        flat[t * 5 + 3] = d3;
        flat[t * 5 + 4] = (j == i) ? 1.0f : 0.0f;
        float dist = sqrtf(__fadd_rn(__fmul_rn(d0, d0), __fmul_rn(d1, d1)));
        maskv[t] = (dist < 1.0f) ? 1.0f : 0.0f;
    }
    if (t >= 128 && t < 132) {
        float v;
        if (t == 128)      v = states[i * 4 + 0] - goals[i * 2 + 0];
        else if (t == 129) v = states[i * 4 + 1] - goals[i * 2 + 1];
        else if (t == 130) v = states[i * 4 + 2];
        else               v = states[i * 4 + 3];
        feat[t] = v;
    }
    __syncthreads();

    // h1[o][p] = relu(b1[o] + sum_c W1[o][c] * flat[c*32+p]), o<64, p<32
    #pragma unroll
    for (int u = 0; u < 8; ++u) {
        int e = t + u * 256;
        int o = e >> 5, p = e & 31;
        float acc = b1[o];
        #pragma unroll
        for (int c = 0; c < 5; ++c)
            acc += W1[o * 5 + c] * flat[c * 32 + p];
        h1[o * 32 + p] = fmaxf(acc, 0.0f);
    }
    __syncthreads();

    // h2[o][p] = relu(b2[o] + sum_c W2[o][c]*h1[c][p]) * mask[p]
    // thread t -> o = t&127, positions p0..p0+15 (half = t>>7)
    {
        const int o  = t & 127;
        const int p0 = (t >> 7) * 16;
        float acc[16];
        #pragma unroll
        for (int pp = 0; pp < 16; ++pp) acc[pp] = 0.0f;
        for (int c = 0; c < 64; ++c) {
            float w = w2t[c * 128 + o];          // consecutive lanes -> consecutive addr
            #pragma unroll
            for (int pp = 0; pp < 16; ++pp)
                acc[pp] += w * h1[c * 32 + p0 + pp];   // wave-uniform addr (broadcast)
        }
        float bb = b2[o];
        #pragma unroll
        for (int pp = 0; pp < 16; ++pp)
            h2m[o * 32 + p0 + pp] = fmaxf(acc[pp] + bb, 0.0f) * maskv[p0 + pp];
    }
    __syncthreads();

    // argmax over p (first max wins, matching jnp.argmax)
    if (t < 128) {
        float best = h2m[t * 32];
        int bi = 0;
        #pragma unroll
        for (int p = 1; p < 32; ++p) {
            float v = h2m[t * 32 + p];
            if (v > best) { best = v; bi = p; }
        }
        feat[t] = (float)bi;
    }
    __syncthreads();

    // dense MLP
    if (t < 64) {
        float acc = bd1[t];
        for (int c = 0; c < 132; ++c) acc += Wd1[t * 132 + c] * feat[c];
        z1s[t] = fmaxf(acc, 0.0f);
    }
    __syncthreads();
    if (t < 128) {
        float acc = bd2[t];
        for (int c = 0; c < 64; ++c) acc += Wd2[t * 64 + c] * z1s[c];
        z2s[t] = fmaxf(acc, 0.0f);
    }
    __syncthreads();
    if (t < 64) {
        float acc = bd3[t];
        for (int c = 0; c < 128; ++c) acc += Wd3[t * 128 + c] * z2s[c];
        z3s[t] = fmaxf(acc, 0.0f);
    }
    __syncthreads();
    if (t < 4) {
        float acc = bd4[t];
        for (int c = 0; c < 64; ++c) acc += Wd4[t * 64 + c] * z3s[c];
        z4s[t] = acc;
    }
    __syncthreads();
    if (t == 0) {
        float k0 = 2.0f / (1.0f + expf(-z4s[0])) + 0.2f;
        float k1 = 2.0f / (1.0f + expf(-z4s[1])) + 0.2f;
        float k2 = 2.0f / (1.0f + expf(-z4s[2])) + 0.2f;
        float k3 = 2.0f / (1.0f + expf(-z4s[3])) + 0.2f;
        float rx = feat[128], ry = feat[129], vx = feat[130], vy = feat[131];
        out[i * 2 + 0] = -(k0 * rx + k1 * vx);
        out[i * 2 + 1] = -(k2 * ry + k3 * vy);
    }
}

extern "C" void kernel_launch(void* const* d_in, const int* in_sizes, int n_in,
                              void* d_out, int out_size, void* d_ws, size_t ws_size,
                              hipStream_t stream)
{
    const float* states = (const float*)d_in[0];
    const float* goals  = (const float*)d_in[1];
    const float* W1  = (const float*)d_in[2];
    const float* b1  = (const float*)d_in[3];
    const float* W2  = (const float*)d_in[4];
    const float* b2  = (const float*)d_in[5];
    const float* Wd1 = (const float*)d_in[6];
    const float* bd1 = (const float*)d_in[7];
    const float* Wd2 = (const float*)d_in[8];
    const float* bd2 = (const float*)d_in[9];
    const float* Wd3 = (const float*)d_in[10];
    const float* bd3 = (const float*)d_in[11];
    const float* Wd4 = (const float*)d_in[12];
    const float* bd4 = (const float*)d_in[13];

    int*   idx = (int*)d_ws;            // 4096*32*4 = 512 KB scratch
    float* out = (float*)d_out;

    topk_kernel<<<NAGENT, 256, 0, stream>>>(states, idx);
    mlp_kernel<<<NAGENT, 256, 0, stream>>>(states, goals, W1, b1, W2, b2,
                                           Wd1, bd1, Wd2, bd2, Wd3, bd3, Wd4, bd4,
                                           idx, out);
}

// Round 2
// 214.066 us; speedup vs baseline: 1.5558x; 1.5558x over previous
//
#include <hip/hip_runtime.h>
#include <math.h>

#define NAGENT 4096
#define TOPK 32
#define AGB 4   // agents per block in mlp_kernel (one wave per agent)

// ---------------------------------------------------------------------------
// Kernel 1: exact top-32 nearest neighbors via histogram filter + exact rank.
// Key = (float_bits(d)<<32)|j  -> ascending d, ties lower index (== jax top_k).
// Positive-float bit ordering == value ordering, so bucketing bits>>20 (2048
// bins) lets us find the bucket containing the 32nd smallest, then rank only
// the ~tens of candidates with bucket <= cutoff. Exact, deterministic.
// ---------------------------------------------------------------------------
__global__ __launch_bounds__(256) void topk_kernel(
    const float* __restrict__ states, int* __restrict__ idx_out)
{
    const int i = blockIdx.x;
    const int t = threadIdx.x;
    __shared__ unsigned int dbits[NAGENT];    // 16 KB
    __shared__ unsigned int hist[2048];       // 8 KB
    __shared__ unsigned int ps[256];          // 1 KB
    __shared__ int cand[NAGENT];              // 16 KB (worst-case safe)
    __shared__ int ccount;
    __shared__ unsigned int cutB;

    #pragma unroll
    for (int u = 0; u < 8; ++u) hist[t + u * 256] = 0u;
    if (t == 0) ccount = 0;

    const float4 si = ((const float4*)states)[i];
    __syncthreads();

    unsigned int mybits[16];
    #pragma unroll
    for (int u = 0; u < 16; ++u) {
        int j = t + u * 256;
        float4 sj = ((const float4*)states)[j];
        float dx = __fsub_rn(si.x, sj.x);
        float dy = __fsub_rn(si.y, sj.y);
        float s  = __fadd_rn(__fadd_rn(__fmul_rn(dx, dx), __fmul_rn(dy, dy)), 1e-4f);
        unsigned int b = __float_as_uint(sqrtf(s));
        dbits[j] = b;
        mybits[u] = b;
        atomicAdd(&hist[b >> 20], 1u);
    }
    __syncthreads();

    // per-thread partial sums of 8 bins, then serial scan over 256 partials
    unsigned int s8 = 0;
    #pragma unroll
    for (int u = 0; u < 8; ++u) s8 += hist[t * 8 + u];
    ps[t] = s8;
    __syncthreads();

    if (t == 0) {
        unsigned int cum = 0;
        int g = 0;
        while (cum + ps[g] < TOPK) { cum += ps[g]; ++g; }
        int b = g * 8;
        for (;;) { cum += hist[b]; if (cum >= TOPK) break; ++b; }
        cutB = (unsigned int)b;
    }
    __syncthreads();

    const unsigned int B = cutB;
    #pragma unroll
    for (int u = 0; u < 16; ++u) {
        if ((mybits[u] >> 20) <= B) {
            int pos = atomicAdd(&ccount, 1);
            cand[pos] = t + u * 256;
        }
    }
    __syncthreads();

    const int C = ccount;   // >= 32 by construction
    for (int q = t; q < C; q += 256) {
        int j = cand[q];
        unsigned long long key = ((unsigned long long)dbits[j] << 32) | (unsigned)j;
        int rank = 0;
        for (int r = 0; r < C; ++r) {
            int jr = cand[r];
            unsigned long long kr = ((unsigned long long)dbits[jr] << 32) | (unsigned)jr;
            rank += (kr < key) ? 1 : 0;
        }
        if (rank < TOPK) idx_out[i * TOPK + rank] = j;
    }
}

// ---------------------------------------------------------------------------
// Kernel 2: fused per-agent network. 4 agents/block, one 64-lane wave each.
// h2 accumulators + argmax in registers; w2t stride-129 (conflict-free);
// h1 rows 16B-aligned for ds_read_b128 broadcast.
// ---------------------------------------------------------------------------
__global__ __launch_bounds__(256) void mlp_kernel(
    const float* __restrict__ states, const float* __restrict__ goals,
    const float* __restrict__ W1,  const float* __restrict__ b1,
    const float* __restrict__ W2,  const float* __restrict__ b2,
    const float* __restrict__ Wd1, const float* __restrict__ bd1,
    const float* __restrict__ Wd2, const float* __restrict__ bd2,
    const float* __restrict__ Wd3, const float* __restrict__ bd3,
    const float* __restrict__ Wd4, const float* __restrict__ bd4,
    const int* __restrict__ idx_in, float* __restrict__ out)
{
    const int t = threadIdx.x;
    const int a = t >> 6;                 // wave id = local agent
    const int l = t & 63;                 // lane
    const int i = blockIdx.x * AGB + a;   // global agent

    __shared__ __attribute__((aligned(16))) float w2t[64 * 129];   // 33 KB, w2t[c*129+o]
    __shared__ __attribute__((aligned(16))) float w1s[320];
    __shared__ __attribute__((aligned(16))) float b1s[64];
    __shared__ __attribute__((aligned(16))) float flat[AGB][160];  // flat[a][k*5+f]
    __shared__ __attribute__((aligned(16))) float maskv[AGB][32];
    __shared__ __attribute__((aligned(16))) float h1[AGB][64 * 32];
    __shared__ __attribute__((aligned(16))) float feat[AGB][132];
    __shared__ __attribute__((aligned(16))) float z1s[AGB][64];
    __shared__ __attribute__((aligned(16))) float z2s[AGB][128];
    __shared__ __attribute__((aligned(16))) float z3s[AGB][64];
    __shared__ __attribute__((aligned(16))) float z4s[AGB][4];

    // ---- stage W2 transposed (stride 129: write bank=(c+o)%32, 2-way = free)
    #pragma unroll
    for (int u = 0; u < 32; ++u) {
        int e = t + u * 256;
        w2t[(e & 63) * 129 + (e >> 6)] = W2[e];
    }
    for (int e = t; e < 320; e += 256) w1s[e] = W1[e];
    if (t < 64) b1s[t] = b1[t];

    // ---- gather xk, mask, tail features (per wave / agent)
    if (l < 32) {
        int j = idx_in[i * TOPK + l];
        float4 sj = ((const float4*)states)[j];
        float4 siv = ((const float4*)states)[i];
        float d0 = siv.x - sj.x;
        float d1 = siv.y - sj.y;
        float d2 = siv.z - sj.z;
        float d3 = siv.w - sj.w;
        flat[a][l * 5 + 0] = d0;
        flat[a][l * 5 + 1] = d1;
        flat[a][l * 5 + 2] = d2;
        flat[a][l * 5 + 3] = d3;
        flat[a][l * 5 + 4] = (j == i) ? 1.0f : 0.0f;
        float dist = sqrtf(__fadd_rn(__fmul_rn(d0, d0), __fmul_rn(d1, d1)));
        maskv[a][l] = (dist < 1.0f) ? 1.0f : 0.0f;
    } else if (l < 36) {
        int f = l - 32;
        float4 siv = ((const float4*)states)[i];
        float2 gi = ((const float2*)goals)[i];
        float v = (f == 0) ? (siv.x - gi.x)
                : (f == 1) ? (siv.y - gi.y)
                : (f == 2) ? siv.z : siv.w;
        feat[a][128 + f] = v;
    }
    __syncthreads();

    // ---- h1[o1][p] = relu(b1[o1] + sum_f W1[o1][f] * X[f][p]), X[f][p]=flat[f*32+p]
    #pragma unroll
    for (int u = 0; u < 32; ++u) {
        int e = u * 64 + l;
        int p = e & 31, o1 = e >> 5;
        float acc = b1s[o1];
        #pragma unroll
        for (int f = 0; f < 5; ++f)
            acc += w1s[o1 * 5 + f] * flat[a][f * 32 + p];
        h1[a][o1 * 32 + p] = fmaxf(acc, 0.0f);
    }
    __syncthreads();

    // ---- h2 (o = l and l+64, all 32 p in registers), then mask+argmax
    float acc0[32], acc1[32];
    #pragma unroll
    for (int p = 0; p < 32; ++p) { acc0[p] = 0.0f; acc1[p] = 0.0f; }
    for (int c = 0; c < 64; ++c) {
        const float4* hr = (const float4*)&h1[a][c * 32];
        float w0 = w2t[c * 129 + l];
        float w1v = w2t[c * 129 + l + 64];
        #pragma unroll
        for (int v = 0; v < 8; ++v) {
            float4 h4 = hr[v];
            acc0[v * 4 + 0] += w0 * h4.x;  acc1[v * 4 + 0] += w1v * h4.x;
            acc0[v * 4 + 1] += w0 * h4.y;  acc1[v * 4 + 1] += w1v * h4.y;
            acc0[v * 4 + 2] += w0 * h4.z;  acc1[v * 4 + 2] += w1v * h4.z;
            acc0[v * 4 + 3] += w0 * h4.w;  acc1[v * 4 + 3] += w1v * h4.w;
        }
    }
    {
        float bb0 = b2[l], bb1 = b2[l + 64];
        float best0 = fmaxf(acc0[0] + bb0, 0.0f) * maskv[a][0]; int bi0 = 0;
        float best1 = fmaxf(acc1[0] + bb1, 0.0f) * maskv[a][0]; int bi1 = 0;
        #pragma unroll
        for (int p = 1; p < 32; ++p) {
            float m = maskv[a][p];
            float v0 = fmaxf(acc0[p] + bb0, 0.0f) * m;
            float v1 = fmaxf(acc1[p] + bb1, 0.0f) * m;
            if (v0 > best0) { best0 = v0; bi0 = p; }
            if (v1 > best1) { best1 = v1; bi1 = p; }
        }
        feat[a][l] = (float)bi0;
        feat[a][l + 64] = (float)bi1;
    }
    __syncthreads();

    // ---- dense MLP (per wave / agent)
    {
        float acc = bd1[l];
        for (int c = 0; c < 132; ++c) acc += Wd1[l * 132 + c] * feat[a][c];
        z1s[a][l] = fmaxf(acc, 0.0f);
    }
    __syncthreads();
    #pragma unroll
    for (int h = 0; h < 2; ++h) {
        int o = l + h * 64;
        float acc = bd2[o];
        for (int c = 0; c < 64; ++c) acc += Wd2[o * 64 + c] * z1s[a][c];
        z2s[a][o] = fmaxf(acc, 0.0f);
    }
    __syncthreads();
    {
        float acc = bd3[l];
        for (int c = 0; c < 128; ++c) acc += Wd3[l * 128 + c] * z2s[a][c];
        z3s[a][l] = fmaxf(acc, 0.0f);
    }
    __syncthreads();
    if (l < 4) {
        float acc = bd4[l];
        for (int c = 0; c < 64; ++c) acc += Wd4[l * 64 + c] * z3s[a][c];
        z4s[a][l] = acc;
    }
    __syncthreads();
    if (l < 2) {
        float ka = 2.0f / (1.0f + expf(-z4s[a][2 * l + 0])) + 0.2f;
        float kb = 2.0f / (1.0f + expf(-z4s[a][2 * l + 1])) + 0.2f;
        float e1 = feat[a][128 + l];   // rx or ry
        float e2 = feat[a][130 + l];   // vx or vy
        out[i * 2 + l] = -(ka * e1 + kb * e2);
    }
}

extern "C" void kernel_launch(void* const* d_in, const int* in_sizes, int n_in,
                              void* d_out, int out_size, void* d_ws, size_t ws_size,
                              hipStream_t stream)
{
    const float* states = (const float*)d_in[0];
    const float* goals  = (const float*)d_in[1];
    const float* W1  = (const float*)d_in[2];
    const float* b1  = (const float*)d_in[3];
    const float* W2  = (const float*)d_in[4];
    const float* b2  = (const float*)d_in[5];
    const float* Wd1 = (const float*)d_in[6];
    const float* bd1 = (const float*)d_in[7];
    const float* Wd2 = (const float*)d_in[8];
    const float* bd2 = (const float*)d_in[9];
    const float* Wd3 = (const float*)d_in[10];
    const float* bd3 = (const float*)d_in[11];
    const float* Wd4 = (const float*)d_in[12];
    const float* bd4 = (const float*)d_in[13];

    int*   idx = (int*)d_ws;            // 4096*32*4 = 512 KB scratch
    float* out = (float*)d_out;

    topk_kernel<<<NAGENT, 256, 0, stream>>>(states, idx);
    mlp_kernel<<<NAGENT / AGB, 256, 0, stream>>>(states, goals, W1, b1, W2, b2,
                                                 Wd1, bd1, Wd2, bd2, Wd3, bd3, Wd4, bd4,
                                                 idx, out);
}

// Round 5
// 202.414 us; speedup vs baseline: 1.6454x; 1.0576x over previous
//
#include <hip/hip_runtime.h>
#include <math.h>

#define NAGENT 4096
#define TOPK 32
#define AGB 4     // agents per block in feat/mlp kernels (one wave per agent)
#define DAGB 16   // agents per block in dense_kernel

// ---------------------------------------------------------------------------
// Kernel 1: exact top-32 nearest neighbors -- VERBATIM from R2 (PASSED).
// Histogram filter (2048 bins = float bits >> 20) + serial cutoff scan +
// exact rank on candidates. Key (dbits<<32)|j == jax top_k semantics.
// ---------------------------------------------------------------------------
__global__ __launch_bounds__(256) void topk_kernel(
    const float* __restrict__ states, int* __restrict__ idx_out)
{
    const int i = blockIdx.x;
    const int t = threadIdx.x;
    __shared__ unsigned int dbits[NAGENT];    // 16 KB
    __shared__ unsigned int hist[2048];       // 8 KB
    __shared__ unsigned int ps[256];          // 1 KB
    __shared__ int cand[NAGENT];              // 16 KB (worst-case safe)
    __shared__ int ccount;
    __shared__ unsigned int cutB;

    #pragma unroll
    for (int u = 0; u < 8; ++u) hist[t + u * 256] = 0u;
    if (t == 0) ccount = 0;

    const float4 si = ((const float4*)states)[i];
    __syncthreads();

    unsigned int mybits[16];
    #pragma unroll
    for (int u = 0; u < 16; ++u) {
        int j = t + u * 256;
        float4 sj = ((const float4*)states)[j];
        float dx = __fsub_rn(si.x, sj.x);
        float dy = __fsub_rn(si.y, sj.y);
        float s  = __fadd_rn(__fadd_rn(__fmul_rn(dx, dx), __fmul_rn(dy, dy)), 1e-4f);
        unsigned int b = __float_as_uint(sqrtf(s));
        dbits[j] = b;
        mybits[u] = b;
        atomicAdd(&hist[b >> 20], 1u);
    }
    __syncthreads();

    unsigned int s8 = 0;
    #pragma unroll
    for (int u = 0; u < 8; ++u) s8 += hist[t * 8 + u];
    ps[t] = s8;
    __syncthreads();

    if (t == 0) {
        unsigned int cum = 0;
        int g = 0;
        while (cum + ps[g] < TOPK) { cum += ps[g]; ++g; }
        int b = g * 8;
        for (;;) { cum += hist[b]; if (cum >= TOPK) break; ++b; }
        cutB = (unsigned int)b;
    }
    __syncthreads();

    const unsigned int B = cutB;
    #pragma unroll
    for (int u = 0; u < 16; ++u) {
        if ((mybits[u] >> 20) <= B) {
            int pos = atomicAdd(&ccount, 1);
            cand[pos] = t + u * 256;
        }
    }
    __syncthreads();

    const int C = ccount;   // >= 32 by construction
    for (int q = t; q < C; q += 256) {
        int j = cand[q];
        unsigned long long key = ((unsigned long long)dbits[j] << 32) | (unsigned)j;
        int rank = 0;
        for (int r = 0; r < C; ++r) {
            int jr = cand[r];
            unsigned long long kr = ((unsigned long long)dbits[jr] << 32) | (unsigned)jr;
            rank += (kr < key) ? 1 : 0;
        }
        if (rank < TOPK) idx_out[i * TOPK + rank] = j;
    }
}

// ---------------------------------------------------------------------------
// Kernel 2a (Path A): per-agent conv stack + argmax -> feat[4096][132] in ws.
// 4 agents/block, one wave each. Barrier structure matches R2's proven mlp.
// ---------------------------------------------------------------------------
__global__ __launch_bounds__(256) void feat_kernel(
    const float* __restrict__ states, const float* __restrict__ goals,
    const float* __restrict__ W1, const float* __restrict__ b1,
    const float* __restrict__ W2, const float* __restrict__ b2,
    const int* __restrict__ idx_in, float* __restrict__ feat_ws)
{
    const int t = threadIdx.x;
    const int a = t >> 6;
    const int l = t & 63;
    const int i = blockIdx.x * AGB + a;

    __shared__ __attribute__((aligned(16))) float w2t[64 * 132];   // 33 KB
    __shared__ __attribute__((aligned(16))) float w1s[320];
    __shared__ __attribute__((aligned(16))) float b1s[64];
    __shared__ __attribute__((aligned(16))) float b2s[128];
    __shared__ __attribute__((aligned(16))) float flat[AGB][160];
    __shared__ __attribute__((aligned(16))) float maskv[AGB][32];
    __shared__ __attribute__((aligned(16))) float h1[AGB][2048];   // 32 KB

    #pragma unroll
    for (int u = 0; u < 32; ++u) {
        int e = t + u * 256;
        w2t[(e & 63) * 132 + (e >> 6)] = W2[e];
    }
    for (int e = t; e < 320; e += 256) w1s[e] = W1[e];
    if (t < 64)  b1s[t] = b1[t];
    if (t < 128) b2s[t] = b2[t];

    if (l < 32) {
        int j = idx_in[i * TOPK + l];
        float4 sj  = ((const float4*)states)[j];
        float4 siv = ((const float4*)states)[i];
        float d0 = siv.x - sj.x;
        float d1 = siv.y - sj.y;
        float d2 = siv.z - sj.z;
        float d3 = siv.w - sj.w;
        flat[a][l * 5 + 0] = d0;
        flat[a][l * 5 + 1] = d1;
        flat[a][l * 5 + 2] = d2;
        flat[a][l * 5 + 3] = d3;
        flat[a][l * 5 + 4] = (j == i) ? 1.0f : 0.0f;
        float dist = sqrtf(__fadd_rn(__fmul_rn(d0, d0), __fmul_rn(d1, d1)));
        maskv[a][l] = (dist < 1.0f) ? 1.0f : 0.0f;
    } else if (l < 36) {
        int f = l - 32;
        float4 siv = ((const float4*)states)[i];
        float2 gi  = ((const float2*)goals)[i];
        float v = (f == 0) ? (siv.x - gi.x)
                : (f == 1) ? (siv.y - gi.y)
                : (f == 2) ? siv.z : siv.w;
        feat_ws[i * 132 + 128 + f] = v;
    }
    __syncthreads();

    // h1[o1][p] = relu(b1[o1] + sum_f W1[o1][f] * X[f][p]), X[f][p]=flat[f*32+p]
    #pragma unroll
    for (int u = 0; u < 32; ++u) {
        int e = u * 64 + l;
        int p = e & 31, o1 = e >> 5;
        float acc = b1s[o1];
        #pragma unroll
        for (int f = 0; f < 5; ++f)
            acc += w1s[o1 * 5 + f] * flat[a][f * 32 + p];
        h1[a][o1 * 32 + p] = fmaxf(acc, 0.0f);
    }
    __syncthreads();   // h1 visible (same barrier structure R2 proved)

    // h2: lane owns o in [ow*8, ow*8+8), p in [pt*8, pt*8+8)
    const int ow = l & 15;     // 16 o-tiles of 8
    const int pt = l >> 4;     // 4 p-tiles of 8
    float acc[8][8];
    #pragma unroll
    for (int k = 0; k < 8; ++k)
        #pragma unroll
        for (int q = 0; q < 8; ++q) acc[k][q] = 0.0f;

    for (int c = 0; c < 64; ++c) {
        float4 wA = *(const float4*)&w2t[c * 132 + ow * 8];
        float4 wB = *(const float4*)&w2t[c * 132 + ow * 8 + 4];
        float4 hA = *(const float4*)&h1[a][c * 32 + pt * 8];
        float4 hB = *(const float4*)&h1[a][c * 32 + pt * 8 + 4];
        float wv[8] = {wA.x, wA.y, wA.z, wA.w, wB.x, wB.y, wB.z, wB.w};
        float hv[8] = {hA.x, hA.y, hA.z, hA.w, hB.x, hB.y, hB.z, hB.w};
        #pragma unroll
        for (int k = 0; k < 8; ++k)
            #pragma unroll
            for (int q = 0; q < 8; ++q)
                acc[k][q] += wv[k] * hv[q];
    }

    // bias + relu + mask + argmax; key = (fbits<<32)|(31-p) => first-max wins
    float4 mA = *(const float4*)&maskv[a][pt * 8];
    float4 mB = *(const float4*)&maskv[a][pt * 8 + 4];
    float mv[8] = {mA.x, mA.y, mA.z, mA.w, mB.x, mB.y, mB.z, mB.w};
    #pragma unroll
    for (int k = 0; k < 8; ++k) {
        float bb = b2s[ow * 8 + k];
        unsigned long long best = 0ull;
        #pragma unroll
        for (int q = 0; q < 8; ++q) {
            float val = fmaxf(acc[k][q] + bb, 0.0f) * mv[q];
            unsigned long long key =
                ((unsigned long long)__float_as_uint(val) << 32)
                | (unsigned int)(31 - (pt * 8 + q));
            if (key > best) best = key;
        }
        // combine the 4 p-tiles: lanes {ow, ow+16, ow+32, ow+48}, all active
        unsigned long long o1 = __shfl_xor(best, 16, 64); if (o1 > best) best = o1;
        unsigned long long o2 = __shfl_xor(best, 32, 64); if (o2 > best) best = o2;
        if (pt == 0) {
            int pbest = 31 - (int)(best & 63ull);
            feat_ws[i * 132 + ow * 8 + k] = (float)pbest;
        }
    }
}

// ---------------------------------------------------------------------------
// Kernel 2b (Path A): batched dense MLP, 16 agents/block, weights in LDS.
// Epilogue through LDS with uniform barrier (no shfl under divergence).
// ---------------------------------------------------------------------------
__global__ __launch_bounds__(256) void dense_kernel(
    const float* __restrict__ feat_ws,
    const float* __restrict__ Wd1, const float* __restrict__ bd1,
    const float* __restrict__ Wd2, const float* __restrict__ bd2,
    const float* __restrict__ Wd3, const float* __restrict__ bd3,
    const float* __restrict__ Wd4, const float* __restrict__ bd4,
    float* __restrict__ out)
{
    const int t = threadIdx.x;
    const int w = t >> 6;
    const int l = t & 63;
    const int A0 = blockIdx.x * DAGB;

    __shared__ float wd1s[64 * 133];
    __shared__ float wd2s[128 * 65];
    __shared__ float wd3s[64 * 129];
    __shared__ float wd4s[4 * 65];
    __shared__ float bd1s[64], bd2s[128], bd3s[64], bd4s[4];
    __shared__ __attribute__((aligned(16))) float fl[DAGB * 132];
    __shared__ __attribute__((aligned(16))) float z1[DAGB][64];
    __shared__ __attribute__((aligned(16))) float z2[DAGB][128];
    __shared__ __attribute__((aligned(16))) float z3[DAGB][64];
    __shared__ float kvs[DAGB][4];

    for (int e = t; e < 8448; e += 256) wd1s[(e / 132) * 133 + (e % 132)] = Wd1[e];
    for (int e = t; e < 8192; e += 256) wd2s[(e >> 6) * 65 + (e & 63)]   = Wd2[e];
    for (int e = t; e < 8192; e += 256) wd3s[(e >> 7) * 129 + (e & 127)] = Wd3[e];
    if (t < 256) wd4s[(t >> 6) * 65 + (t & 63)] = Wd4[t];
    if (t < 64)  bd1s[t] = bd1[t];
    if (t < 128) bd2s[t] = bd2[t];
    if (t < 64)  bd3s[t] = bd3[t];
    if (t < 4)   bd4s[t] = bd4[t];
    for (int e = t; e < DAGB * 132; e += 256) fl[e] = feat_ws[A0 * 132 + e];
    __syncthreads();

    const int gbase = w * 4;   // this wave's 4 agents (local)

    // L1: lane = output o (64), 4 agents
    {
        float a0 = bd1s[l], a1 = bd1s[l], a2 = bd1s[l], a3 = bd1s[l];
        for (int k = 0; k < 33; ++k) {
            float w0 = wd1s[l * 133 + 4 * k + 0];
            float w1v = wd1s[l * 133 + 4 * k + 1];
            float w2v = wd1s[l * 133 + 4 * k + 2];
            float w3 = wd1s[l * 133 + 4 * k + 3];
            float4 f0 = *(const float4*)&fl[(gbase + 0) * 132 + 4 * k];
            float4 f1 = *(const float4*)&fl[(gbase + 1) * 132 + 4 * k];
            float4 f2 = *(const float4*)&fl[(gbase + 2) * 132 + 4 * k];
            float4 f3 = *(const float4*)&fl[(gbase + 3) * 132 + 4 * k];
            a0 += w0 * f0.x; a0 += w1v * f0.y; a0 += w2v * f0.z; a0 += w3 * f0.w;
            a1 += w0 * f1.x; a1 += w1v * f1.y; a1 += w2v * f1.z; a1 += w3 * f1.w;
            a2 += w0 * f2.x; a2 += w1v * f2.y; a2 += w2v * f2.z; a2 += w3 * f2.w;
            a3 += w0 * f3.x; a3 += w1v * f3.y; a3 += w2v * f3.z; a3 += w3 * f3.w;
        }
        z1[gbase + 0][l] = fmaxf(a0, 0.0f);
        z1[gbase + 1][l] = fmaxf(a1, 0.0f);
        z1[gbase + 2][l] = fmaxf(a2, 0.0f);
        z1[gbase + 3][l] = fmaxf(a3, 0.0f);
    }

    // L2: lane = outputs l and l+64, 4 agents
    {
        float accA[4], accB[4];
        #pragma unroll
        for (int g = 0; g < 4; ++g) { accA[g] = bd2s[l]; accB[g] = bd2s[l + 64]; }
        for (int k = 0; k < 16; ++k) {
            float wa0 = wd2s[l * 65 + 4 * k + 0], wa1 = wd2s[l * 65 + 4 * k + 1];
            float wa2 = wd2s[l * 65 + 4 * k + 2], wa3 = wd2s[l * 65 + 4 * k + 3];
            float wb0 = wd2s[(l + 64) * 65 + 4 * k + 0], wb1 = wd2s[(l + 64) * 65 + 4 * k + 1];
            float wb2 = wd2s[(l + 64) * 65 + 4 * k + 2], wb3 = wd2s[(l + 64) * 65 + 4 * k + 3];
            #pragma unroll
            for (int g = 0; g < 4; ++g) {
                float4 f = *(const float4*)&z1[gbase + g][4 * k];
                accA[g] += wa0 * f.x; accA[g] += wa1 * f.y;
                accA[g] += wa2 * f.z; accA[g] += wa3 * f.w;
                accB[g] += wb0 * f.x; accB[g] += wb1 * f.y;
                accB[g] += wb2 * f.z; accB[g] += wb3 * f.w;
            }
        }
        #pragma unroll
        for (int g = 0; g < 4; ++g) {
            z2[gbase + g][l]      = fmaxf(accA[g], 0.0f);
            z2[gbase + g][l + 64] = fmaxf(accB[g], 0.0f);
        }
    }

    // L3: lane = output o (64), 4 agents
    {
        float acc[4];
        #pragma unroll
        for (int g = 0; g < 4; ++g) acc[g] = bd3s[l];
        for (int k = 0; k < 32; ++k) {
            float w0 = wd3s[l * 129 + 4 * k + 0], w1v = wd3s[l * 129 + 4 * k + 1];
            float w2v = wd3s[l * 129 + 4 * k + 2], w3 = wd3s[l * 129 + 4 * k + 3];
            #pragma unroll
            for (int g = 0; g < 4; ++g) {
                float4 f = *(const float4*)&z2[gbase + g][4 * k];
                acc[g] += w0 * f.x; acc[g] += w1v * f.y;
                acc[g] += w2v * f.z; acc[g] += w3 * f.w;
            }
        }
        #pragma unroll
        for (int g = 0; g < 4; ++g) z3[gbase + g][l] = fmaxf(acc[g], 0.0f);
    }

    // L4 + sigmoid -> LDS (lanes 0..15: agent g=l>>2, gain o=l&3)
    if (l < 16) {
        int g = l >> 2, o = l & 3;
        float acc = bd4s[o];
        for (int c = 0; c < 64; ++c) acc += wd4s[o * 65 + c] * z3[gbase + g][c];
        kvs[gbase + g][o] = 2.0f / (1.0f + expf(-acc)) + 0.2f;
    }
    __syncthreads();   // uniform barrier; kvs visible

    // output: lanes 0..7 of each wave -> (agent g=l>>1, axis=l&1)
    if (l < 8) {
        int g = l >> 1, axis = l & 1;
        float ka = kvs[gbase + g][2 * axis + 0];
        float kb = kvs[gbase + g][2 * axis + 1];
        float rel = fl[(gbase + g) * 132 + 128 + axis];
        float vel = fl[(gbase + g) * 132 + 130 + axis];
        out[(A0 + gbase + g) * 2 + axis] = -(ka * rel + kb * vel);
    }
}

// ---------------------------------------------------------------------------
// Path B fallback: R2's proven fused mlp_kernel (PASSED; no extra workspace).
// ---------------------------------------------------------------------------
__global__ __launch_bounds__(256) void mlp_fallback_kernel(
    const float* __restrict__ states, const float* __restrict__ goals,
    const float* __restrict__ W1,  const float* __restrict__ b1,
    const float* __restrict__ W2,  const float* __restrict__ b2,
    const float* __restrict__ Wd1, const float* __restrict__ bd1,
    const float* __restrict__ Wd2, const float* __restrict__ bd2,
    const float* __restrict__ Wd3, const float* __restrict__ bd3,
    const float* __restrict__ Wd4, const float* __restrict__ bd4,
    const int* __restrict__ idx_in, float* __restrict__ out)
{
    const int t = threadIdx.x;
    const int a = t >> 6;
    const int l = t & 63;
    const int i = blockIdx.x * AGB + a;

    __shared__ __attribute__((aligned(16))) float w2t[64 * 129];
    __shared__ __attribute__((aligned(16))) float w1s[320];
    __shared__ __attribute__((aligned(16))) float b1s[64];
    __shared__ __attribute__((aligned(16))) float flat[AGB][160];
    __shared__ __attribute__((aligned(16))) float maskv[AGB][32];
    __shared__ __attribute__((aligned(16))) float h1[AGB][64 * 32];
    __shared__ __attribute__((aligned(16))) float feat[AGB][132];
    __shared__ __attribute__((aligned(16))) float z1s[AGB][64];
    __shared__ __attribute__((aligned(16))) float z2s[AGB][128];
    __shared__ __attribute__((aligned(16))) float z3s[AGB][64];
    __shared__ __attribute__((aligned(16))) float z4s[AGB][4];

    #pragma unroll
    for (int u = 0; u < 32; ++u) {
        int e = t + u * 256;
        w2t[(e & 63) * 129 + (e >> 6)] = W2[e];
    }
    for (int e = t; e < 320; e += 256) w1s[e] = W1[e];
    if (t < 64) b1s[t] = b1[t];

    if (l < 32) {
        int j = idx_in[i * TOPK + l];
        float4 sj = ((const float4*)states)[j];
        float4 siv = ((const float4*)states)[i];
        float d0 = siv.x - sj.x;
        float d1 = siv.y - sj.y;
        float d2 = siv.z - sj.z;
        float d3 = siv.w - sj.w;
        flat[a][l * 5 + 0] = d0;
        flat[a][l * 5 + 1] = d1;
        flat[a][l * 5 + 2] = d2;
        flat[a][l * 5 + 3] = d3;
        flat[a][l * 5 + 4] = (j == i) ? 1.0f : 0.0f;
        float dist = sqrtf(__fadd_rn(__fmul_rn(d0, d0), __fmul_rn(d1, d1)));
        maskv[a][l] = (dist < 1.0f) ? 1.0f : 0.0f;
    } else if (l < 36) {
        int f = l - 32;
        float4 siv = ((const float4*)states)[i];
        float2 gi = ((const float2*)goals)[i];
        float v = (f == 0) ? (siv.x - gi.x)
                : (f == 1) ? (siv.y - gi.y)
                : (f == 2) ? siv.z : siv.w;
        feat[a][128 + f] = v;
    }
    __syncthreads();

    #pragma unroll
    for (int u = 0; u < 32; ++u) {
        int e = u * 64 + l;
        int p = e & 31, o1 = e >> 5;
        float acc = b1s[o1];
        #pragma unroll
        for (int f = 0; f < 5; ++f)
            acc += w1s[o1 * 5 + f] * flat[a][f * 32 + p];
        h1[a][o1 * 32 + p] = fmaxf(acc, 0.0f);
    }
    __syncthreads();

    float acc0[32], acc1[32];
    #pragma unroll
    for (int p = 0; p < 32; ++p) { acc0[p] = 0.0f; acc1[p] = 0.0f; }
    for (int c = 0; c < 64; ++c) {
        const float4* hr = (const float4*)&h1[a][c * 32];
        float w0 = w2t[c * 129 + l];
        float w1v = w2t[c * 129 + l + 64];
        #pragma unroll
        for (int v = 0; v < 8; ++v) {
            float4 h4 = hr[v];
            acc0[v * 4 + 0] += w0 * h4.x;  acc1[v * 4 + 0] += w1v * h4.x;
            acc0[v * 4 + 1] += w0 * h4.y;  acc1[v * 4 + 1] += w1v * h4.y;
            acc0[v * 4 + 2] += w0 * h4.z;  acc1[v * 4 + 2] += w1v * h4.z;
            acc0[v * 4 + 3] += w0 * h4.w;  acc1[v * 4 + 3] += w1v * h4.w;
        }
    }
    {
        float bb0 = b2[l], bb1 = b2[l + 64];
        float best0 = fmaxf(acc0[0] + bb0, 0.0f) * maskv[a][0]; int bi0 = 0;
        float best1 = fmaxf(acc1[0] + bb1, 0.0f) * maskv[a][0]; int bi1 = 0;
        #pragma unroll
        for (int p = 1; p < 32; ++p) {
            float m = maskv[a][p];
            float v0 = fmaxf(acc0[p] + bb0, 0.0f) * m;
            float v1 = fmaxf(acc1[p] + bb1, 0.0f) * m;
            if (v0 > best0) { best0 = v0; bi0 = p; }
            if (v1 > best1) { best1 = v1; bi1 = p; }
        }
        feat[a][l] = (float)bi0;
        feat[a][l + 64] = (float)bi1;
    }
    __syncthreads();

    {
        float acc = bd1[l];
        for (int c = 0; c < 132; ++c) acc += Wd1[l * 132 + c] * feat[a][c];
        z1s[a][l] = fmaxf(acc, 0.0f);
    }
    __syncthreads();
    #pragma unroll
    for (int h = 0; h < 2; ++h) {
        int o = l + h * 64;
        float acc = bd2[o];
        for (int c = 0; c < 64; ++c) acc += Wd2[o * 64 + c] * z1s[a][c];
        z2s[a][o] = fmaxf(acc, 0.0f);
    }
    __syncthreads();
    {
        float acc = bd3[l];
        for (int c = 0; c < 128; ++c) acc += Wd3[l * 128 + c] * z2s[a][c];
        z3s[a][l] = fmaxf(acc, 0.0f);
    }
    __syncthreads();
    if (l < 4) {
        float acc = bd4[l];
        for (int c = 0; c < 64; ++c) acc += Wd4[l * 64 + c] * z3s[a][c];
        z4s[a][l] = acc;
    }
    __syncthreads();
    if (l < 2) {
        float ka = 2.0f / (1.0f + expf(-z4s[a][2 * l + 0])) + 0.2f;
        float kb = 2.0f / (1.0f + expf(-z4s[a][2 * l + 1])) + 0.2f;
        float e1 = feat[a][128 + l];
        float e2 = feat[a][130 + l];
        out[i * 2 + l] = -(ka * e1 + kb * e2);
    }
}

extern "C" void kernel_launch(void* const* d_in, const int* in_sizes, int n_in,
                              void* d_out, int out_size, void* d_ws, size_t ws_size,
                              hipStream_t stream)
{
    const float* states = (const float*)d_in[0];
    const float* goals  = (const float*)d_in[1];
    const float* W1  = (const float*)d_in[2];
    const float* b1  = (const float*)d_in[3];
    const float* W2  = (const float*)d_in[4];
    const float* b2  = (const float*)d_in[5];
    const float* Wd1 = (const float*)d_in[6];
    const float* bd1 = (const float*)d_in[7];
    const float* Wd2 = (const float*)d_in[8];
    const float* bd2 = (const float*)d_in[9];
    const float* Wd3 = (const float*)d_in[10];
    const float* bd3 = (const float*)d_in[11];
    const float* Wd4 = (const float*)d_in[12];
    const float* bd4 = (const float*)d_in[13];

    const size_t idx_bytes  = (size_t)NAGENT * TOPK * 4;        // 512 KB
    const size_t feat_bytes = (size_t)NAGENT * 132 * 4;         // ~2.06 MB
    int*   idx = (int*)d_ws;
    float* out = (float*)d_out;

    topk_kernel<<<NAGENT, 256, 0, stream>>>(states, idx);

    if (ws_size >= idx_bytes + feat_bytes) {
        float* feat_ws = (float*)((char*)d_ws + idx_bytes);
        feat_kernel<<<NAGENT / AGB, 256, 0, stream>>>(states, goals, W1, b1, W2, b2,
                                                      idx, feat_ws);
        dense_kernel<<<NAGENT / DAGB, 256, 0, stream>>>(feat_ws, Wd1, bd1, Wd2, bd2,
                                                        Wd3, bd3, Wd4, bd4, out);
    } else {
        mlp_fallback_kernel<<<NAGENT / AGB, 256, 0, stream>>>(states, goals, W1, b1,
                                                              W2, b2, Wd1, bd1, Wd2, bd2,
                                                              Wd3, bd3, Wd4, bd4, idx, out);
    }
}

// Round 6
// 156.517 us; speedup vs baseline: 2.1279x; 1.2932x over previous
//
#include <hip/hip_runtime.h>
#include <math.h>

#define NAGENT 4096
#define TOPK 32
#define AGB 4     // agents per block in feat kernel (one wave per agent)
#define DAGB 16   // agents per block in dense_kernel
#define CANDCAP 2048

// ---------------------------------------------------------------------------
// Kernel 1: exact top-32 nearest neighbors.
// Histogram (1024 bins = positive-float bits >> 21; bit order == value order)
// -> two-level PARALLEL partial sums (ps[256] over 4 bins, ps2[32] over 32)
// -> short serial walk (<=44 dependent reads) to the cutoff bucket
// -> collect packed keys (bits<<32)|j for bucket <= cutoff (superset of top-32)
// -> exact rank by key. Key order == jax top_k(-d) (ascending d, ties lower j).
// Distance ops non-contracted to match numpy rounding exactly.
// ---------------------------------------------------------------------------
__global__ __launch_bounds__(256) void topk_kernel(
    const float* __restrict__ states, int* __restrict__ idx_out)
{
    const int i = blockIdx.x;
    const int t = threadIdx.x;
    __shared__ unsigned int hist[1024];                // 4 KB
    __shared__ unsigned int ps[256];                   // 1 KB (sums of 4 bins)
    __shared__ unsigned int ps2[32];                   // 128 B (sums of 32 bins)
    __shared__ unsigned long long cand[CANDCAP];       // 16 KB
    __shared__ int ccount;
    __shared__ unsigned int cutB;

    #pragma unroll
    for (int u = 0; u < 4; ++u) hist[t + u * 256] = 0u;
    if (t == 0) ccount = 0;

    const float4 si = ((const float4*)states)[i];
    __syncthreads();

    unsigned int mybits[16];
    #pragma unroll
    for (int u = 0; u < 16; ++u) {
        int j = t + u * 256;
        float4 sj = ((const float4*)states)[j];
        float dx = __fsub_rn(si.x, sj.x);
        float dy = __fsub_rn(si.y, sj.y);
        float s  = __fadd_rn(__fadd_rn(__fmul_rn(dx, dx), __fmul_rn(dy, dy)), 1e-4f);
        unsigned int b = __float_as_uint(sqrtf(s));
        mybits[u] = b;
        atomicAdd(&hist[b >> 21], 1u);
    }
    __syncthreads();

    // level-1 partials: thread t sums bins [4t, 4t+4)
    ps[t] = hist[t * 4 + 0] + hist[t * 4 + 1] + hist[t * 4 + 2] + hist[t * 4 + 3];
    __syncthreads();
    // level-2 partials: thread t<32 sums ps[8t..8t+8) (= bins [32t, 32t+32))
    if (t < 32) {
        unsigned int s = 0;
        #pragma unroll
        for (int q = 0; q < 8; ++q) s += ps[t * 8 + q];
        ps2[t] = s;
    }
    __syncthreads();

    // short serial walk: <= 32 + 8 + 4 dependent LDS reads
    if (t == 0) {
        unsigned int cum = 0;
        int g2 = 0;
        while (cum + ps2[g2] < TOPK) { cum += ps2[g2]; ++g2; }
        int g1 = g2 * 8;
        while (cum + ps[g1] < TOPK) { cum += ps[g1]; ++g1; }
        int b = g1 * 4;
        for (;;) { cum += hist[b]; if (cum >= TOPK) break; ++b; }
        cutB = (unsigned int)b;
    }
    __syncthreads();

    const unsigned int B = cutB;
    #pragma unroll
    for (int u = 0; u < 16; ++u) {
        if ((mybits[u] >> 21) <= B) {
            int pos = atomicAdd(&ccount, 1);
            if (pos < CANDCAP)
                cand[pos] = ((unsigned long long)mybits[u] << 32)
                          | (unsigned int)(t + u * 256);
        }
    }
    __syncthreads();

    const int C = (ccount < CANDCAP) ? ccount : CANDCAP;   // >= 32 by construction
    for (int q = t; q < C; q += 256) {
        unsigned long long key = cand[q];
        int rank = 0;
        for (int r = 0; r < C; ++r) rank += (cand[r] < key) ? 1 : 0;
        if (rank < TOPK) idx_out[i * TOPK + rank] = (int)(key & 0xffffffffu);
    }
}

// ---------------------------------------------------------------------------
// Kernel 2a: per-agent conv stack + argmax -> feat[4096][132] in ws.
// VERBATIM from R5 (PASSED).
// ---------------------------------------------------------------------------
__global__ __launch_bounds__(256) void feat_kernel(
    const float* __restrict__ states, const float* __restrict__ goals,
    const float* __restrict__ W1, const float* __restrict__ b1,
    const float* __restrict__ W2, const float* __restrict__ b2,
    const int* __restrict__ idx_in, float* __restrict__ feat_ws)
{
    const int t = threadIdx.x;
    const int a = t >> 6;
    const int l = t & 63;
    const int i = blockIdx.x * AGB + a;

    __shared__ __attribute__((aligned(16))) float w2t[64 * 132];   // 33 KB
    __shared__ __attribute__((aligned(16))) float w1s[320];
    __shared__ __attribute__((aligned(16))) float b1s[64];
    __shared__ __attribute__((aligned(16))) float b2s[128];
    __shared__ __attribute__((aligned(16))) float flat[AGB][160];
    __shared__ __attribute__((aligned(16))) float maskv[AGB][32];
    __shared__ __attribute__((aligned(16))) float h1[AGB][2048];   // 32 KB

    #pragma unroll
    for (int u = 0; u < 32; ++u) {
        int e = t + u * 256;
        w2t[(e & 63) * 132 + (e >> 6)] = W2[e];
    }
    for (int e = t; e < 320; e += 256) w1s[e] = W1[e];
    if (t < 64)  b1s[t] = b1[t];
    if (t < 128) b2s[t] = b2[t];

    if (l < 32) {
        int j = idx_in[i * TOPK + l];
        float4 sj  = ((const float4*)states)[j];
        float4 siv = ((const float4*)states)[i];
        float d0 = siv.x - sj.x;
        float d1 = siv.y - sj.y;
        float d2 = siv.z - sj.z;
        float d3 = siv.w - sj.w;
        flat[a][l * 5 + 0] = d0;
        flat[a][l * 5 + 1] = d1;
        flat[a][l * 5 + 2] = d2;
        flat[a][l * 5 + 3] = d3;
        flat[a][l * 5 + 4] = (j == i) ? 1.0f : 0.0f;
        float dist = sqrtf(__fadd_rn(__fmul_rn(d0, d0), __fmul_rn(d1, d1)));
        maskv[a][l] = (dist < 1.0f) ? 1.0f : 0.0f;
    } else if (l < 36) {
        int f = l - 32;
        float4 siv = ((const float4*)states)[i];
        float2 gi  = ((const float2*)goals)[i];
        float v = (f == 0) ? (siv.x - gi.x)
                : (f == 1) ? (siv.y - gi.y)
                : (f == 2) ? siv.z : siv.w;
        feat_ws[i * 132 + 128 + f] = v;
    }
    __syncthreads();

    #pragma unroll
    for (int u = 0; u < 32; ++u) {
        int e = u * 64 + l;
        int p = e & 31, o1 = e >> 5;
        float acc = b1s[o1];
        #pragma unroll
        for (int f = 0; f < 5; ++f)
            acc += w1s[o1 * 5 + f] * flat[a][f * 32 + p];
        h1[a][o1 * 32 + p] = fmaxf(acc, 0.0f);
    }
    __syncthreads();

    const int ow = l & 15;     // 16 o-tiles of 8
    const int pt = l >> 4;     // 4 p-tiles of 8
    float acc[8][8];
    #pragma unroll
    for (int k = 0; k < 8; ++k)
        #pragma unroll
        for (int q = 0; q < 8; ++q) acc[k][q] = 0.0f;

    for (int c = 0; c < 64; ++c) {
        float4 wA = *(const float4*)&w2t[c * 132 + ow * 8];
        float4 wB = *(const float4*)&w2t[c * 132 + ow * 8 + 4];
        float4 hA = *(const float4*)&h1[a][c * 32 + pt * 8];
        float4 hB = *(const float4*)&h1[a][c * 32 + pt * 8 + 4];
        float wv[8] = {wA.x, wA.y, wA.z, wA.w, wB.x, wB.y, wB.z, wB.w};
        float hv[8] = {hA.x, hA.y, hA.z, hA.w, hB.x, hB.y, hB.z, hB.w};
        #pragma unroll
        for (int k = 0; k < 8; ++k)
            #pragma unroll
            for (int q = 0; q < 8; ++q)
                acc[k][q] += wv[k] * hv[q];
    }

    float4 mA = *(const float4*)&maskv[a][pt * 8];
    float4 mB = *(const float4*)&maskv[a][pt * 8 + 4];
    float mv[8] = {mA.x, mA.y, mA.z, mA.w, mB.x, mB.y, mB.z, mB.w};
    #pragma unroll
    for (int k = 0; k < 8; ++k) {
        float bb = b2s[ow * 8 + k];
        unsigned long long best = 0ull;
        #pragma unroll
        for (int q = 0; q < 8; ++q) {
            float val = fmaxf(acc[k][q] + bb, 0.0f) * mv[q];
            unsigned long long key =
                ((unsigned long long)__float_as_uint(val) << 32)
                | (unsigned int)(31 - (pt * 8 + q));
            if (key > best) best = key;
        }
        unsigned long long o1 = __shfl_xor(best, 16, 64); if (o1 > best) best = o1;
        unsigned long long o2 = __shfl_xor(best, 32, 64); if (o2 > best) best = o2;
        if (pt == 0) {
            int pbest = 31 - (int)(best & 63ull);
            feat_ws[i * 132 + ow * 8 + k] = (float)pbest;
        }
    }
}

// ---------------------------------------------------------------------------
// Kernel 2b: batched dense MLP, 16 agents/block. VERBATIM from R5 (PASSED).
// ---------------------------------------------------------------------------
__global__ __launch_bounds__(256) void dense_kernel(
    const float* __restrict__ feat_ws,
    const float* __restrict__ Wd1, const float* __restrict__ bd1,
    const float* __restrict__ Wd2, const float* __restrict__ bd2,
    const float* __restrict__ Wd3, const float* __restrict__ bd3,
    const float* __restrict__ Wd4, const float* __restrict__ bd4,
    float* __restrict__ out)
{
    const int t = threadIdx.x;
    const int w = t >> 6;
    const int l = t & 63;
    const int A0 = blockIdx.x * DAGB;

    __shared__ float wd1s[64 * 133];
    __shared__ float wd2s[128 * 65];
    __shared__ float wd3s[64 * 129];
    __shared__ float wd4s[4 * 65];
    __shared__ float bd1s[64], bd2s[128], bd3s[64], bd4s[4];
    __shared__ __attribute__((aligned(16))) float fl[DAGB * 132];
    __shared__ __attribute__((aligned(16))) float z1[DAGB][64];
    __shared__ __attribute__((aligned(16))) float z2[DAGB][128];
    __shared__ __attribute__((aligned(16))) float z3[DAGB][64];
    __shared__ float kvs[DAGB][4];

    for (int e = t; e < 8448; e += 256) wd1s[(e / 132) * 133 + (e % 132)] = Wd1[e];
    for (int e = t; e < 8192; e += 256) wd2s[(e >> 6) * 65 + (e & 63)]   = Wd2[e];
    for (int e = t; e < 8192; e += 256) wd3s[(e >> 7) * 129 + (e & 127)] = Wd3[e];
    if (t < 256) wd4s[(t >> 6) * 65 + (t & 63)] = Wd4[t];
    if (t < 64)  bd1s[t] = bd1[t];
    if (t < 128) bd2s[t] = bd2[t];
    if (t < 64)  bd3s[t] = bd3[t];
    if (t < 4)   bd4s[t] = bd4[t];
    for (int e = t; e < DAGB * 132; e += 256) fl[e] = feat_ws[A0 * 132 + e];
    __syncthreads();

    const int gbase = w * 4;

    {
        float a0 = bd1s[l], a1 = bd1s[l], a2 = bd1s[l], a3 = bd1s[l];
        for (int k = 0; k < 33; ++k) {
            float w0 = wd1s[l * 133 + 4 * k + 0];
            float w1v = wd1s[l * 133 + 4 * k + 1];
            float w2v = wd1s[l * 133 + 4 * k + 2];
            float w3 = wd1s[l * 133 + 4 * k + 3];
            float4 f0 = *(const float4*)&fl[(gbase + 0) * 132 + 4 * k];
            float4 f1 = *(const float4*)&fl[(gbase + 1) * 132 + 4 * k];
            float4 f2 = *(const float4*)&fl[(gbase + 2) * 132 + 4 * k];
            float4 f3 = *(const float4*)&fl[(gbase + 3) * 132 + 4 * k];
            a0 += w0 * f0.x; a0 += w1v * f0.y; a0 += w2v * f0.z; a0 += w3 * f0.w;
            a1 += w0 * f1.x; a1 += w1v * f1.y; a1 += w2v * f1.z; a1 += w3 * f1.w;
            a2 += w0 * f2.x; a2 += w1v * f2.y; a2 += w2v * f2.z; a2 += w3 * f2.w;
            a3 += w0 * f3.x; a3 += w1v * f3.y; a3 += w2v * f3.z; a3 += w3 * f3.w;
        }
        z1[gbase + 0][l] = fmaxf(a0, 0.0f);
        z1[gbase + 1][l] = fmaxf(a1, 0.0f);
        z1[gbase + 2][l] = fmaxf(a2, 0.0f);
        z1[gbase + 3][l] = fmaxf(a3, 0.0f);
    }

    {
        float accA[4], accB[4];
        #pragma unroll
        for (int g = 0; g < 4; ++g) { accA[g] = bd2s[l]; accB[g] = bd2s[l + 64]; }
        for (int k = 0; k < 16; ++k) {
            float wa0 = wd2s[l * 65 + 4 * k + 0], wa1 = wd2s[l * 65 + 4 * k + 1];
            float wa2 = wd2s[l * 65 + 4 * k + 2], wa3 = wd2s[l * 65 + 4 * k + 3];
            float wb0 = wd2s[(l + 64) * 65 + 4 * k + 0], wb1 = wd2s[(l + 64) * 65 + 4 * k + 1];
            float wb2 = wd2s[(l + 64) * 65 + 4 * k + 2], wb3 = wd2s[(l + 64) * 65 + 4 * k + 3];
            #pragma unroll
            for (int g = 0; g < 4; ++g) {
                float4 f = *(const float4*)&z1[gbase + g][4 * k];
                accA[g] += wa0 * f.x; accA[g] += wa1 * f.y;
                accA[g] += wa2 * f.z; accA[g] += wa3 * f.w;
                accB[g] += wb0 * f.x; accB[g] += wb1 * f.y;
                accB[g] += wb2 * f.z; accB[g] += wb3 * f.w;
            }
        }
        #pragma unroll
        for (int g = 0; g < 4; ++g) {
            z2[gbase + g][l]      = fmaxf(accA[g], 0.0f);
            z2[gbase + g][l + 64] = fmaxf(accB[g], 0.0f);
        }
    }

    {
        float acc[4];
        #pragma unroll
        for (int g = 0; g < 4; ++g) acc[g] = bd3s[l];
        for (int k = 0; k < 32; ++k) {
            float w0 = wd3s[l * 129 + 4 * k + 0], w1v = wd3s[l * 129 + 4 * k + 1];
            float w2v = wd3s[l * 129 + 4 * k + 2], w3 = wd3s[l * 129 + 4 * k + 3];
            #pragma unroll
            for (int g = 0; g < 4; ++g) {
                float4 f = *(const float4*)&z2[gbase + g][4 * k];
                acc[g] += w0 * f.x; acc[g] += w1v * f.y;
                acc[g] += w2v * f.z; acc[g] += w3 * f.w;
            }
        }
        #pragma unroll
        for (int g = 0; g < 4; ++g) z3[gbase + g][l] = fmaxf(acc[g], 0.0f);
    }

    if (l < 16) {
        int g = l >> 2, o = l & 3;
        float acc = bd4s[o];
        for (int c = 0; c < 64; ++c) acc += wd4s[o * 65 + c] * z3[gbase + g][c];
        kvs[gbase + g][o] = 2.0f / (1.0f + expf(-acc)) + 0.2f;
    }
    __syncthreads();

    if (l < 8) {
        int g = l >> 1, axis = l & 1;
        float ka = kvs[gbase + g][2 * axis + 0];
        float kb = kvs[gbase + g][2 * axis + 1];
        float rel = fl[(gbase + g) * 132 + 128 + axis];
        float vel = fl[(gbase + g) * 132 + 130 + axis];
        out[(A0 + gbase + g) * 2 + axis] = -(ka * rel + kb * vel);
    }
}

extern "C" void kernel_launch(void* const* d_in, const int* in_sizes, int n_in,
                              void* d_out, int out_size, void* d_ws, size_t ws_size,
                              hipStream_t stream)
{
    const float* states = (const float*)d_in[0];
    const float* goals  = (const float*)d_in[1];
    const float* W1  = (const float*)d_in[2];
    const float* b1  = (const float*)d_in[3];
    const float* W2  = (const float*)d_in[4];
    const float* b2  = (const float*)d_in[5];
    const float* Wd1 = (const float*)d_in[6];
    const float* bd1 = (const float*)d_in[7];
    const float* Wd2 = (const float*)d_in[8];
    const float* bd2 = (const float*)d_in[9];
    const float* Wd3 = (const float*)d_in[10];
    const float* bd3 = (const float*)d_in[11];
    const float* Wd4 = (const float*)d_in[12];
    const float* bd4 = (const float*)d_in[13];

    const size_t idx_bytes = (size_t)NAGENT * TOPK * 4;        // 512 KB
    int*   idx     = (int*)d_ws;
    float* feat_ws = (float*)((char*)d_ws + idx_bytes);        // 4096*132*4 ~ 2.06 MB
    float* out     = (float*)d_out;

    topk_kernel<<<NAGENT, 256, 0, stream>>>(states, idx);
    feat_kernel<<<NAGENT / AGB, 256, 0, stream>>>(states, goals, W1, b1, W2, b2,
                                                  idx, feat_ws);
    dense_kernel<<<NAGENT / DAGB, 256, 0, stream>>>(feat_ws, Wd1, bd1, Wd2, bd2,
                                                    Wd3, bd3, Wd4, bd4, out);
}

// Round 7
// 155.100 us; speedup vs baseline: 2.1473x; 1.0091x over previous
//
#include <hip/hip_runtime.h>
#include <math.h>

#define NAGENT 4096
#define TOPK 32
#define AGB 8     // agents per block in feat kernel (one wave per agent)
#define DAGB 16   // agents per block in dense_kernel
#define CANDCAP 2048

// ---------------------------------------------------------------------------
// Kernel 1: exact top-32 nearest neighbors. VERBATIM from R6 (PASSED).
// ---------------------------------------------------------------------------
__global__ __launch_bounds__(256) void topk_kernel(
    const float* __restrict__ states, int* __restrict__ idx_out)
{
    const int i = blockIdx.x;
    const int t = threadIdx.x;
    __shared__ unsigned int hist[1024];                // 4 KB
    __shared__ unsigned int ps[256];                   // 1 KB (sums of 4 bins)
    __shared__ unsigned int ps2[32];                   // 128 B (sums of 32 bins)
    __shared__ unsigned long long cand[CANDCAP];       // 16 KB
    __shared__ int ccount;
    __shared__ unsigned int cutB;

    #pragma unroll
    for (int u = 0; u < 4; ++u) hist[t + u * 256] = 0u;
    if (t == 0) ccount = 0;

    const float4 si = ((const float4*)states)[i];
    __syncthreads();

    unsigned int mybits[16];
    #pragma unroll
    for (int u = 0; u < 16; ++u) {
        int j = t + u * 256;
        float4 sj = ((const float4*)states)[j];
        float dx = __fsub_rn(si.x, sj.x);
        float dy = __fsub_rn(si.y, sj.y);
        float s  = __fadd_rn(__fadd_rn(__fmul_rn(dx, dx), __fmul_rn(dy, dy)), 1e-4f);
        unsigned int b = __float_as_uint(sqrtf(s));
        mybits[u] = b;
        atomicAdd(&hist[b >> 21], 1u);
    }
    __syncthreads();

    ps[t] = hist[t * 4 + 0] + hist[t * 4 + 1] + hist[t * 4 + 2] + hist[t * 4 + 3];
    __syncthreads();
    if (t < 32) {
        unsigned int s = 0;
        #pragma unroll
        for (int q = 0; q < 8; ++q) s += ps[t * 8 + q];
        ps2[t] = s;
    }
    __syncthreads();

    if (t == 0) {
        unsigned int cum = 0;
        int g2 = 0;
        while (cum + ps2[g2] < TOPK) { cum += ps2[g2]; ++g2; }
        int g1 = g2 * 8;
        while (cum + ps[g1] < TOPK) { cum += ps[g1]; ++g1; }
        int b = g1 * 4;
        for (;;) { cum += hist[b]; if (cum >= TOPK) break; ++b; }
        cutB = (unsigned int)b;
    }
    __syncthreads();

    const unsigned int B = cutB;
    #pragma unroll
    for (int u = 0; u < 16; ++u) {
        if ((mybits[u] >> 21) <= B) {
            int pos = atomicAdd(&ccount, 1);
            if (pos < CANDCAP)
                cand[pos] = ((unsigned long long)mybits[u] << 32)
                          | (unsigned int)(t + u * 256);
        }
    }
    __syncthreads();

    const int C = (ccount < CANDCAP) ? ccount : CANDCAP;
    for (int q = t; q < C; q += 256) {
        unsigned long long key = cand[q];
        int rank = 0;
        for (int r = 0; r < C; ++r) rank += (cand[r] < key) ? 1 : 0;
        if (rank < TOPK) idx_out[i * TOPK + rank] = (int)(key & 0xffffffffu);
    }
}

// ---------------------------------------------------------------------------
// Kernel 2a: per-agent conv stack + argmax -> feat[4096][132] in ws.
// R7 changes vs R6: AGB 4->8 (staging amortized 2x, 1 block/CU, 8 waves);
// W2 split into w2a/w2b stride-68 so lane float4 reads start 16 B apart
// (2-way b128 = free) instead of 32 B (4-way). FMA order unchanged.
// ---------------------------------------------------------------------------
__global__ __launch_bounds__(512) void feat_kernel(
    const float* __restrict__ states, const float* __restrict__ goals,
    const float* __restrict__ W1, const float* __restrict__ b1,
    const float* __restrict__ W2, const float* __restrict__ b2,
    const int* __restrict__ idx_in, float* __restrict__ feat_ws)
{
    const int t = threadIdx.x;
    const int a = t >> 6;
    const int l = t & 63;
    const int i = blockIdx.x * AGB + a;

    // w2a holds W2[o][c] for o%8<4 at [c*68 + (o>>3)*4 + (o&3)]; w2b for o%8>=4
    __shared__ __attribute__((aligned(16))) float w2a[64 * 68];    // 17 KB
    __shared__ __attribute__((aligned(16))) float w2b[64 * 68];    // 17 KB
    __shared__ __attribute__((aligned(16))) float w1s[320];
    __shared__ __attribute__((aligned(16))) float b1s[64];
    __shared__ __attribute__((aligned(16))) float b2s[128];
    __shared__ __attribute__((aligned(16))) float flat[AGB][160];
    __shared__ __attribute__((aligned(16))) float maskv[AGB][32];
    __shared__ __attribute__((aligned(16))) float h1[AGB][2048];   // 64 KB

    // stage W2 split (coalesced global reads)
    #pragma unroll
    for (int u = 0; u < 16; ++u) {
        int e = t + u * 512;
        int o = e >> 6, c = e & 63;
        float v = W2[e];
        int dst = c * 68 + ((o >> 3) << 2) + (o & 3);
        if (o & 4) w2b[dst] = v; else w2a[dst] = v;
    }
    for (int e = t; e < 320; e += 512) w1s[e] = W1[e];
    if (t < 64)  b1s[t] = b1[t];
    else if (t >= 128 && t < 256) b2s[t - 128] = b2[t - 128];

    if (l < 32) {
        int j = idx_in[i * TOPK + l];
        float4 sj  = ((const float4*)states)[j];
        float4 siv = ((const float4*)states)[i];
        float d0 = siv.x - sj.x;
        float d1 = siv.y - sj.y;
        float d2 = siv.z - sj.z;
        float d3 = siv.w - sj.w;
        flat[a][l * 5 + 0] = d0;
        flat[a][l * 5 + 1] = d1;
        flat[a][l * 5 + 2] = d2;
        flat[a][l * 5 + 3] = d3;
        flat[a][l * 5 + 4] = (j == i) ? 1.0f : 0.0f;
        float dist = sqrtf(__fadd_rn(__fmul_rn(d0, d0), __fmul_rn(d1, d1)));
        maskv[a][l] = (dist < 1.0f) ? 1.0f : 0.0f;
    } else if (l < 36) {
        int f = l - 32;
        float4 siv = ((const float4*)states)[i];
        float2 gi  = ((const float2*)goals)[i];
        float v = (f == 0) ? (siv.x - gi.x)
                : (f == 1) ? (siv.y - gi.y)
                : (f == 2) ? siv.z : siv.w;
        feat_ws[i * 132 + 128 + f] = v;
    }
    __syncthreads();

    // h1[o1][p] = relu(b1[o1] + sum_f W1[o1][f] * flat[f*32+p])
    #pragma unroll
    for (int u = 0; u < 32; ++u) {
        int e = u * 64 + l;
        int p = e & 31, o1 = e >> 5;
        float acc = b1s[o1];
        #pragma unroll
        for (int f = 0; f < 5; ++f)
            acc += w1s[o1 * 5 + f] * flat[a][f * 32 + p];
        h1[a][o1 * 32 + p] = fmaxf(acc, 0.0f);
    }
    __syncthreads();

    // h2: lane owns o in [ow*8, ow*8+8), p in [pt*8, pt*8+8)
    const int ow = l & 15;
    const int pt = l >> 4;
    float acc[8][8];
    #pragma unroll
    for (int k = 0; k < 8; ++k)
        #pragma unroll
        for (int q = 0; q < 8; ++q) acc[k][q] = 0.0f;

    for (int c = 0; c < 64; ++c) {
        float4 wA = *(const float4*)&w2a[c * 68 + ow * 4];   // o = ow*8+0..3
        float4 wB = *(const float4*)&w2b[c * 68 + ow * 4];   // o = ow*8+4..7
        float4 hA = *(const float4*)&h1[a][c * 32 + pt * 8];
        float4 hB = *(const float4*)&h1[a][c * 32 + pt * 8 + 4];
        float wv[8] = {wA.x, wA.y, wA.z, wA.w, wB.x, wB.y, wB.z, wB.w};
        float hv[8] = {hA.x, hA.y, hA.z, hA.w, hB.x, hB.y, hB.z, hB.w};
        #pragma unroll
        for (int k = 0; k < 8; ++k)
            #pragma unroll
            for (int q = 0; q < 8; ++q)
                acc[k][q] += wv[k] * hv[q];
    }

    float4 mA = *(const float4*)&maskv[a][pt * 8];
    float4 mB = *(const float4*)&maskv[a][pt * 8 + 4];
    float mv[8] = {mA.x, mA.y, mA.z, mA.w, mB.x, mB.y, mB.z, mB.w};
    #pragma unroll
    for (int k = 0; k < 8; ++k) {
        float bb = b2s[ow * 8 + k];
        unsigned long long best = 0ull;
        #pragma unroll
        for (int q = 0; q < 8; ++q) {
            float val = fmaxf(acc[k][q] + bb, 0.0f) * mv[q];
            unsigned long long key =
                ((unsigned long long)__float_as_uint(val) << 32)
                | (unsigned int)(31 - (pt * 8 + q));
            if (key > best) best = key;
        }
        unsigned long long o1 = __shfl_xor(best, 16, 64); if (o1 > best) best = o1;
        unsigned long long o2 = __shfl_xor(best, 32, 64); if (o2 > best) best = o2;
        if (pt == 0) {
            int pbest = 31 - (int)(best & 63ull);
            feat_ws[i * 132 + ow * 8 + k] = (float)pbest;
        }
    }
}

// ---------------------------------------------------------------------------
// Kernel 2b: batched dense MLP, 16 agents/block. VERBATIM from R5/R6 (PASSED).
// ---------------------------------------------------------------------------
__global__ __launch_bounds__(256) void dense_kernel(
    const float* __restrict__ feat_ws,
    const float* __restrict__ Wd1, const float* __restrict__ bd1,
    const float* __restrict__ Wd2, const float* __restrict__ bd2,
    const float* __restrict__ Wd3, const float* __restrict__ bd3,
    const float* __restrict__ Wd4, const float* __restrict__ bd4,
    float* __restrict__ out)
{
    const int t = threadIdx.x;
    const int w = t >> 6;
    const int l = t & 63;
    const int A0 = blockIdx.x * DAGB;

    __shared__ float wd1s[64 * 133];
    __shared__ float wd2s[128 * 65];
    __shared__ float wd3s[64 * 129];
    __shared__ float wd4s[4 * 65];
    __shared__ float bd1s[64], bd2s[128], bd3s[64], bd4s[4];
    __shared__ __attribute__((aligned(16))) float fl[DAGB * 132];
    __shared__ __attribute__((aligned(16))) float z1[DAGB][64];
    __shared__ __attribute__((aligned(16))) float z2[DAGB][128];
    __shared__ __attribute__((aligned(16))) float z3[DAGB][64];
    __shared__ float kvs[DAGB][4];

    for (int e = t; e < 8448; e += 256) wd1s[(e / 132) * 133 + (e % 132)] = Wd1[e];
    for (int e = t; e < 8192; e += 256) wd2s[(e >> 6) * 65 + (e & 63)]   = Wd2[e];
    for (int e = t; e < 8192; e += 256) wd3s[(e >> 7) * 129 + (e & 127)] = Wd3[e];
    if (t < 256) wd4s[(t >> 6) * 65 + (t & 63)] = Wd4[t];
    if (t < 64)  bd1s[t] = bd1[t];
    if (t < 128) bd2s[t] = bd2[t];
    if (t < 64)  bd3s[t] = bd3[t];
    if (t < 4)   bd4s[t] = bd4[t];
    for (int e = t; e < DAGB * 132; e += 256) fl[e] = feat_ws[A0 * 132 + e];
    __syncthreads();

    const int gbase = w * 4;

    {
        float a0 = bd1s[l], a1 = bd1s[l], a2 = bd1s[l], a3 = bd1s[l];
        for (int k = 0; k < 33; ++k) {
            float w0 = wd1s[l * 133 + 4 * k + 0];
            float w1v = wd1s[l * 133 + 4 * k + 1];
            float w2v = wd1s[l * 133 + 4 * k + 2];
            float w3 = wd1s[l * 133 + 4 * k + 3];
            float4 f0 = *(const float4*)&fl[(gbase + 0) * 132 + 4 * k];
            float4 f1 = *(const float4*)&fl[(gbase + 1) * 132 + 4 * k];
            float4 f2 = *(const float4*)&fl[(gbase + 2) * 132 + 4 * k];
            float4 f3 = *(const float4*)&fl[(gbase + 3) * 132 + 4 * k];
            a0 += w0 * f0.x; a0 += w1v * f0.y; a0 += w2v * f0.z; a0 += w3 * f0.w;
            a1 += w0 * f1.x; a1 += w1v * f1.y; a1 += w2v * f1.z; a1 += w3 * f1.w;
            a2 += w0 * f2.x; a2 += w1v * f2.y; a2 += w2v * f2.z; a2 += w3 * f2.w;
            a3 += w0 * f3.x; a3 += w1v * f3.y; a3 += w2v * f3.z; a3 += w3 * f3.w;
        }
        z1[gbase + 0][l] = fmaxf(a0, 0.0f);
        z1[gbase + 1][l] = fmaxf(a1, 0.0f);
        z1[gbase + 2][l] = fmaxf(a2, 0.0f);
        z1[gbase + 3][l] = fmaxf(a3, 0.0f);
    }

    {
        float accA[4], accB[4];
        #pragma unroll
        for (int g = 0; g < 4; ++g) { accA[g] = bd2s[l]; accB[g] = bd2s[l + 64]; }
        for (int k = 0; k < 16; ++k) {
            float wa0 = wd2s[l * 65 + 4 * k + 0], wa1 = wd2s[l * 65 + 4 * k + 1];
            float wa2 = wd2s[l * 65 + 4 * k + 2], wa3 = wd2s[l * 65 + 4 * k + 3];
            float wb0 = wd2s[(l + 64) * 65 + 4 * k + 0], wb1 = wd2s[(l + 64) * 65 + 4 * k + 1];
            float wb2 = wd2s[(l + 64) * 65 + 4 * k + 2], wb3 = wd2s[(l + 64) * 65 + 4 * k + 3];
            #pragma unroll
            for (int g = 0; g < 4; ++g) {
                float4 f = *(const float4*)&z1[gbase + g][4 * k];
                accA[g] += wa0 * f.x; accA[g] += wa1 * f.y;
                accA[g] += wa2 * f.z; accA[g] += wa3 * f.w;
                accB[g] += wb0 * f.x; accB[g] += wb1 * f.y;
                accB[g] += wb2 * f.z; accB[g] += wb3 * f.w;
            }
        }
        #pragma unroll
        for (int g = 0; g < 4; ++g) {
            z2[gbase + g][l]      = fmaxf(accA[g], 0.0f);
            z2[gbase + g][l + 64] = fmaxf(accB[g], 0.0f);
        }
    }

    {
        float acc[4];
        #pragma unroll
        for (int g = 0; g < 4; ++g) acc[g] = bd3s[l];
        for (int k = 0; k < 32; ++k) {
            float w0 = wd3s[l * 129 + 4 * k + 0], w1v = wd3s[l * 129 + 4 * k + 1];
            float w2v = wd3s[l * 129 + 4 * k + 2], w3 = wd3s[l * 129 + 4 * k + 3];
            #pragma unroll
            for (int g = 0; g < 4; ++g) {
                float4 f = *(const float4*)&z2[gbase + g][4 * k];
                acc[g] += w0 * f.x; acc[g] += w1v * f.y;
                acc[g] += w2v * f.z; acc[g] += w3 * f.w;
            }
        }
        #pragma unroll
        for (int g = 0; g < 4; ++g) z3[gbase + g][l] = fmaxf(acc[g], 0.0f);
    }

    if (l < 16) {
        int g = l >> 2, o = l & 3;
        float acc = bd4s[o];
        for (int c = 0; c < 64; ++c) acc += wd4s[o * 65 + c] * z3[gbase + g][c];
        kvs[gbase + g][o] = 2.0f / (1.0f + expf(-acc)) + 0.2f;
    }
    __syncthreads();

    if (l < 8) {
        int g = l >> 1, axis = l & 1;
        float ka = kvs[gbase + g][2 * axis + 0];
        float kb = kvs[gbase + g][2 * axis + 1];
        float rel = fl[(gbase + g) * 132 + 128 + axis];
        float vel = fl[(gbase + g) * 132 + 130 + axis];
        out[(A0 + gbase + g) * 2 + axis] = -(ka * rel + kb * vel);
    }
}

extern "C" void kernel_launch(void* const* d_in, const int* in_sizes, int n_in,
                              void* d_out, int out_size, void* d_ws, size_t ws_size,
                              hipStream_t stream)
{
    const float* states = (const float*)d_in[0];
    const float* goals  = (const float*)d_in[1];
    const float* W1  = (const float*)d_in[2];
    const float* b1  = (const float*)d_in[3];
    const float* W2  = (const float*)d_in[4];
    const float* b2  = (const float*)d_in[5];
    const float* Wd1 = (const float*)d_in[6];
    const float* bd1 = (const float*)d_in[7];
    const float* Wd2 = (const float*)d_in[8];
    const float* bd2 = (const float*)d_in[9];
    const float* Wd3 = (const float*)d_in[10];
    const float* bd3 = (const float*)d_in[11];
    const float* Wd4 = (const float*)d_in[12];
    const float* bd4 = (const float*)d_in[13];

    const size_t idx_bytes = (size_t)NAGENT * TOPK * 4;        // 512 KB
    int*   idx     = (int*)d_ws;
    float* feat_ws = (float*)((char*)d_ws + idx_bytes);        // 4096*132*4 ~ 2.06 MB
    float* out     = (float*)d_out;

    topk_kernel<<<NAGENT, 256, 0, stream>>>(states, idx);
    feat_kernel<<<NAGENT / AGB, 512, 0, stream>>>(states, goals, W1, b1, W2, b2,
                                                  idx, feat_ws);
    dense_kernel<<<NAGENT / DAGB, 256, 0, stream>>>(feat_ws, Wd1, bd1, Wd2, bd2,
                                                    Wd3, bd3, Wd4, bd4, out);
}